// Round 1
// baseline (288.535 us; speedup 1.0000x reference)
//
#include <hip/hip_runtime.h>
#include <math.h>

// PANLoss: dice(regions) + 0.5*dice(kernels) + 0.25*(agg + dis)
// Strategy: one streaming pass computes per-batch sums into ws (atomicAdd),
// then a tiny finalize kernel computes the 5 scalar outputs.
//
// Per-batch workspace layout (NACC=51 floats):
//   [0..8]   ct[seg]      count of pixels with tlab==seg
//   [9..17]  ck[seg]      count of pixels with klab==seg
//   [18..26] S_t[seg]     sum of s2 over tlab==seg
//   [27..35] S_k[seg]     sum of s2 over klab==seg
//   [36..44] S_same[seg]  sum of s2 over tlab==seg && klab==seg
//   [45..47] regions: sum(p*g), sum(p*p), sum(g*g)
//   [48..50] kernels: sum(p*g), sum(p*p), sum(g*g)

#define NSEG 9
#define NACC 51
#define NBATCH 16
#define EPSF 1e-5f

__device__ __forceinline__ float wave_reduce_sum(float v) {
#pragma unroll
    for (int off = 32; off > 0; off >>= 1)
        v += __shfl_down(v, off, 64);
    return v;
}

__device__ __forceinline__ float sigm(float x) {
    return 1.0f / (1.0f + __expf(-x));
}

__global__ __launch_bounds__(256) void pan_main(
    const float* __restrict__ pred_r, const float* __restrict__ gt_r,
    const float* __restrict__ pred_k, const float* __restrict__ gt_k,
    const float* __restrict__ sim,
    const int* __restrict__ tlab, const int* __restrict__ klab,
    float* __restrict__ ws, int npix)
{
    const int b = blockIdx.y;
    const int nvec = npix >> 2;  // float4 groups per batch
    const long long base = (long long)b * npix;
    const long long sbase = (long long)b * 4 * npix;

    const float4* pr4 = (const float4*)(pred_r + base);
    const float4* gr4 = (const float4*)(gt_r + base);
    const float4* pk4 = (const float4*)(pred_k + base);
    const float4* gk4 = (const float4*)(gt_k + base);
    const float4* c0_4 = (const float4*)(sim + sbase);
    const float4* c1_4 = (const float4*)(sim + sbase + npix);
    const float4* c2_4 = (const float4*)(sim + sbase + 2LL * npix);
    const float4* c3_4 = (const float4*)(sim + sbase + 3LL * npix);
    const int4* tl4 = (const int4*)(tlab + base);
    const int4* kl4 = (const int4*)(klab + base);

    float ctA[NSEG], ckA[NSEG], StA[NSEG], SkA[NSEG], SsA[NSEG];
#pragma unroll
    for (int s = 0; s < NSEG; ++s) {
        ctA[s] = 0.0f; ckA[s] = 0.0f; StA[s] = 0.0f; SkA[s] = 0.0f; SsA[s] = 0.0f;
    }
    float rpg = 0.0f, rpp = 0.0f, rgg = 0.0f;
    float kpg = 0.0f, kpp = 0.0f, kgg = 0.0f;

    for (int i = blockIdx.x * blockDim.x + threadIdx.x; i < nvec;
         i += gridDim.x * blockDim.x) {
        float4 pr = pr4[i], gr = gr4[i], pk = pk4[i], gk = gk4[i];
        float4 c0 = c0_4[i], c1 = c1_4[i], c2 = c2_4[i], c3 = c3_4[i];
        int4 tl = tl4[i], kl = kl4[i];

        // --- dice sums (regions) ---
        {
            float p;
            p = sigm(pr.x); rpg += p * gr.x; rpp += p * p; rgg += gr.x * gr.x;
            p = sigm(pr.y); rpg += p * gr.y; rpp += p * p; rgg += gr.y * gr.y;
            p = sigm(pr.z); rpg += p * gr.z; rpp += p * p; rgg += gr.z * gr.z;
            p = sigm(pr.w); rpg += p * gr.w; rpp += p * p; rgg += gr.w * gr.w;
        }
        // --- dice sums (kernels) ---
        {
            float p;
            p = sigm(pk.x); kpg += p * gk.x; kpp += p * p; kgg += gk.x * gk.x;
            p = sigm(pk.y); kpg += p * gk.y; kpp += p * p; kgg += gk.y * gk.y;
            p = sigm(pk.z); kpg += p * gk.z; kpp += p * p; kgg += gk.z * gk.z;
            p = sigm(pk.w); kpg += p * gk.w; kpp += p * p; kgg += gk.w * gk.w;
        }

        // --- per-pixel squared feature norm over 4 channels ---
        float s2x = c0.x * c0.x + c1.x * c1.x + c2.x * c2.x + c3.x * c3.x;
        float s2y = c0.y * c0.y + c1.y * c1.y + c2.y * c2.y + c3.y * c3.y;
        float s2z = c0.z * c0.z + c1.z * c1.z + c2.z * c2.z + c3.z * c3.z;
        float s2w = c0.w * c0.w + c1.w * c1.w + c2.w * c2.w + c3.w * c3.w;

        // --- branchless segment accumulation (fully unrolled -> registers) ---
#pragma unroll
        for (int s = 0; s < NSEG; ++s) {
            {
                bool t = (tl.x == s), k = (kl.x == s);
                ctA[s] += t ? 1.0f : 0.0f;
                ckA[s] += k ? 1.0f : 0.0f;
                StA[s] += t ? s2x : 0.0f;
                SkA[s] += k ? s2x : 0.0f;
                SsA[s] += (t && k) ? s2x : 0.0f;
            }
            {
                bool t = (tl.y == s), k = (kl.y == s);
                ctA[s] += t ? 1.0f : 0.0f;
                ckA[s] += k ? 1.0f : 0.0f;
                StA[s] += t ? s2y : 0.0f;
                SkA[s] += k ? s2y : 0.0f;
                SsA[s] += (t && k) ? s2y : 0.0f;
            }
            {
                bool t = (tl.z == s), k = (kl.z == s);
                ctA[s] += t ? 1.0f : 0.0f;
                ckA[s] += k ? 1.0f : 0.0f;
                StA[s] += t ? s2z : 0.0f;
                SkA[s] += k ? s2z : 0.0f;
                SsA[s] += (t && k) ? s2z : 0.0f;
            }
            {
                bool t = (tl.w == s), k = (kl.w == s);
                ctA[s] += t ? 1.0f : 0.0f;
                ckA[s] += k ? 1.0f : 0.0f;
                StA[s] += t ? s2w : 0.0f;
                SkA[s] += k ? s2w : 0.0f;
                SsA[s] += (t && k) ? s2w : 0.0f;
            }
        }
    }

    // --- block reduction: wave shuffle -> LDS -> one atomicAdd per quantity ---
    __shared__ float red[4][NACC];
    const int lane = threadIdx.x & 63;
    const int wv = threadIdx.x >> 6;

#pragma unroll
    for (int s = 0; s < NSEG; ++s) {
        float r;
        r = wave_reduce_sum(ctA[s]); if (lane == 0) red[wv][s] = r;
        r = wave_reduce_sum(ckA[s]); if (lane == 0) red[wv][NSEG + s] = r;
        r = wave_reduce_sum(StA[s]); if (lane == 0) red[wv][2 * NSEG + s] = r;
        r = wave_reduce_sum(SkA[s]); if (lane == 0) red[wv][3 * NSEG + s] = r;
        r = wave_reduce_sum(SsA[s]); if (lane == 0) red[wv][4 * NSEG + s] = r;
    }
    {
        float r;
        r = wave_reduce_sum(rpg); if (lane == 0) red[wv][45] = r;
        r = wave_reduce_sum(rpp); if (lane == 0) red[wv][46] = r;
        r = wave_reduce_sum(rgg); if (lane == 0) red[wv][47] = r;
        r = wave_reduce_sum(kpg); if (lane == 0) red[wv][48] = r;
        r = wave_reduce_sum(kpp); if (lane == 0) red[wv][49] = r;
        r = wave_reduce_sum(kgg); if (lane == 0) red[wv][50] = r;
    }
    __syncthreads();
    if (threadIdx.x < NACC) {
        float s = red[0][threadIdx.x] + red[1][threadIdx.x] +
                  red[2][threadIdx.x] + red[3][threadIdx.x];
        atomicAdd(&ws[b * NACC + threadIdx.x], s);
    }
}

__global__ __launch_bounds__(64) void pan_finalize(
    const float* __restrict__ ws, float* __restrict__ out)
{
    const int b = threadIdx.x;
    float dice_r = 0.0f, dice_k = 0.0f, lagg = 0.0f, ldis = 0.0f;

    if (b < NBATCH) {
        const float* w = ws + b * NACC;
        // dice losses
        {
            float pg = w[45], pp = w[46], gg = w[47];
            dice_r = 1.0f - (2.0f * pg + EPSF) / ((pp + EPSF) + (gg + EPSF));
            pg = w[48]; pp = w[49]; gg = w[50];
            dice_k = 1.0f - (2.0f * pg + EPSF) / ((pp + EPSF) + (gg + EPSF));
        }
        float a[8];
#pragma unroll
        for (int i = 1; i < NSEG; ++i) {
            float ct = w[i], ck = w[NSEG + i];
            float St = w[2 * NSEG + i], Sk = w[3 * NSEG + i], Ss = w[4 * NSEG + i];
            float inv = 1.0f / (ck + 1.0f);
            float omi = 1.0f - inv;
            float n2 = omi * omi * Ss + (St - Ss) + inv * inv * (Sk - Ss);
            float nrm = sqrtf(n2);
            float d = nrm - 0.5f;  // SIGMA_AGG (no clamp — matches reference)
            lagg += logf(d * d + 1.0f) / (ct + 1.0f);
            float ckd = ck + 0.001f;
            a[i - 1] = Sk / (ckd * ckd);
        }
#pragma unroll
        for (int i = 0; i < 8; ++i) {
#pragma unroll
            for (int j = i + 1; j < 8; ++j) {
                float pair = 3.0f - sqrtf(a[i] + a[j]);  // SIGMA_DIS
                ldis += logf(pair * pair + 1.0f);
            }
        }
        ldis *= (1.0f / 56.0f);  // K_MAX*(K_MAX-1)
    }

    // sum across the 16 active lanes (lanes >= 16 hold zeros)
    dice_r = wave_reduce_sum(dice_r);
    dice_k = wave_reduce_sum(dice_k);
    lagg = wave_reduce_sum(lagg);
    ldis = wave_reduce_sum(ldis);

    if (threadIdx.x == 0) {
        float loss = dice_r + 0.5f * dice_k + 0.25f * (lagg + ldis);
        out[0] = loss;
        out[1] = dice_r;
        out[2] = dice_k;
        out[3] = lagg;
        out[4] = ldis;
    }
}

extern "C" void kernel_launch(void* const* d_in, const int* in_sizes, int n_in,
                              void* d_out, int out_size, void* d_ws, size_t ws_size,
                              hipStream_t stream) {
    const float* pred_r = (const float*)d_in[0];
    const float* gt_r   = (const float*)d_in[1];
    const float* pred_k = (const float*)d_in[2];
    const float* gt_k   = (const float*)d_in[3];
    const float* sim    = (const float*)d_in[4];
    const int*   tlab   = (const int*)d_in[5];
    const int*   klab   = (const int*)d_in[6];
    float* out = (float*)d_out;
    float* ws  = (float*)d_ws;

    const int npix = in_sizes[0] / NBATCH;  // 640*640 = 409600

    hipMemsetAsync(ws, 0, NBATCH * NACC * sizeof(float), stream);

    dim3 grid(128, NBATCH);
    pan_main<<<grid, 256, 0, stream>>>(pred_r, gt_r, pred_k, gt_k, sim,
                                       tlab, klab, ws, npix);
    pan_finalize<<<1, 64, 0, stream>>>(ws, out);
}